// Round 7
// baseline (368.514 us; speedup 1.0000x reference)
//
#include <hip/hip_runtime.h>
#include <cstdint>

namespace {
constexpr int B = 8, C = 3, H = 1024, W = 1024;
constexpr int HO = 256, WO = 256, K2 = 9;
constexpr int HP = H + 2, WP = W + 2;
constexpr int HW = H * W, HOWO = HO * WO;
constexpr int WIN = 100, LSTR = 101;   // 100x100 f32 window, +1 pad stride
// window covers 16x16 outputs: span 64 px + 2 taps + ±16 px jitter + reflect slack

__device__ __forceinline__ int reflect_src(int p, int n) {
    // padded index p in [0, n+1] -> source index in [0, n-1] (numpy 'reflect')
    int s = p - 1;
    s = (s < 0) ? -s : s;
    s = (s >= n) ? (2 * n - 2 - s) : s;
    return s;
}

// LDS-gather kernel. Lessons encoded:
//  - R2: 2 outputs/thread (108-reg tap state) spilled -> 1 output/thread, 45 regs.
//  - R4: VGPR cap 64 spills batches -> __launch_bounds__(256,4) = cap 128.
//  - R5/R6: scattered VMEM has ~constant per-cacheline service cost -> gather
//    from LDS instead; VMEM does only coalesced staging.
//  - R3: XCD = blockIdx%8 = batch keeps each image's reuse in one L2.
__global__ __launch_bounds__(256, 4) void ds_lds(
    const float* __restrict__ img,
    const float* __restrict__ kern,
    const float* __restrict__ offh,
    const float* __restrict__ offv,
    const float* __restrict__ ou_p,
    float* __restrict__ out) {
    __shared__ float tile[WIN * LSTR];   // 40400 B -> 4 blocks/CU

    const int tid = threadIdx.x;
    const int b  = blockIdx.x & 7;       // XCD id = batch
    const int t  = blockIdx.x >> 3;      // 0..255 tile id, w-fastest per XCD
    const int th = t >> 4, tw = t & 15;
    const int h = th * 16 + (tid >> 4);
    const int w = tw * 16 + (tid & 15);
    const int ylo = th * 64 - 16;        // window origin (source coords)
    const int xlo = tw * 64 - 16;

    const float ou = ou_p[0];
    const float cy = h * 4 + 1.5f;
    const float cx = w * 4 + 1.5f;

    // ---- Phase 1: params -> packed tap state (45 VGPRs) ----
    int   pk0[K2], pk1[K2];              // (ly<<16)|(lx&0xffff), window coords
    float aw[K2], bw[K2], kv[K2];
    int inmask = 0;
    {
        size_t pb = ((size_t)b * K2) * (size_t)HOWO + (size_t)h * WO + w;
#pragma unroll
        for (int k = 0; k < K2; ++k) {
            size_t o = pb + (size_t)(k * HOWO);
            kv[k] = kern[o];
            float py = cy + (float)(k / 3) + offv[o] * ou;
            float px = cx + (float)(k % 3) + offh[o] * ou;
            float y0f = floorf(py), x0f = floorf(px);
            bw[k] = py - y0f;
            aw[k] = px - x0f;
            int y0 = min(max((int)y0f, 0), HP - 1);
            int x0 = min(max((int)x0f, 0), WP - 1);
            int y1 = min(y0 + 1, HP - 1);
            int x1 = min(x0 + 1, WP - 1);
            int sy0 = reflect_src(y0, H), sy1 = reflect_src(y1, H);
            int sx0 = reflect_src(x0, W), sx1 = reflect_src(x1, W);
            int ly0 = sy0 - ylo, ly1 = sy1 - ylo;
            int lx0 = sx0 - xlo, lx1 = sx1 - xlo;
            pk0[k] = (ly0 << 16) | (lx0 & 0xffff);
            pk1[k] = (ly1 << 16) | (lx1 & 0xffff);
            int in = ((unsigned)ly0 < WIN) & ((unsigned)ly1 < WIN) &
                     ((unsigned)lx0 < WIN) & ((unsigned)lx1 < WIN);
            inmask |= in << k;
        }
    }

    // ---- Phase 2: per channel, stage window to LDS then gather from LDS ----
    float acc[C];
    const float* __restrict__ icb = img + (size_t)b * (C * HW);
#pragma unroll
    for (int c = 0; c < C; ++c) {
        const float* __restrict__ ic = icb + (size_t)c * HW;
        __syncthreads();                 // prev channel's gathers done
#pragma unroll 4
        for (int j = 0; j < 40; ++j) {   // 100*100 px / 256 threads
            int i = tid + j * 256;
            if (i < WIN * WIN) {
                int ly = i / WIN, lx = i - ly * WIN;
                int gy = min(max(ylo + ly, 0), H - 1);  // clamped dupes: never read
                int gx = min(max(xlo + lx, 0), W - 1);
                tile[ly * LSTR + lx] = ic[(gy << 10) + gx];
            }
        }
        __syncthreads();

        float a = 0.f;
#pragma unroll
        for (int k = 0; k < K2; ++k) {
            int ly0 = pk0[k] >> 16, lx0 = (pk0[k] << 16) >> 16;
            int ly1 = pk1[k] >> 16, lx1 = (pk1[k] << 16) >> 16;
            float v00, v01, v10, v11;
            if ((inmask >> k) & 1) {
                v00 = tile[ly0 * LSTR + lx0];
                v01 = tile[ly0 * LSTR + lx1];
                v10 = tile[ly1 * LSTR + lx0];
                v11 = tile[ly1 * LSTR + lx1];
            } else {                     // |offset*4| > 16 px: exact global path
                v00 = ic[((ly0 + ylo) << 10) + (lx0 + xlo)];
                v01 = ic[((ly0 + ylo) << 10) + (lx1 + xlo)];
                v10 = ic[((ly1 + ylo) << 10) + (lx0 + xlo)];
                v11 = ic[((ly1 + ylo) << 10) + (lx1 + xlo)];
            }
            float tt = v00 + aw[k] * (v01 - v00);
            float uu = v10 + aw[k] * (v11 - v10);
            a += kv[k] * (tt + bw[k] * (uu - tt));
        }
        acc[c] = a;
    }

    size_t obase = ((size_t)b * C) * (size_t)HOWO + (size_t)h * WO + w;
#pragma unroll
    for (int c = 0; c < C; ++c)
        out[obase + (size_t)c * HOWO] = acc[c];
}
} // namespace

extern "C" void kernel_launch(void* const* d_in, const int* in_sizes, int n_in,
                              void* d_out, int out_size, void* d_ws, size_t ws_size,
                              hipStream_t stream) {
    const float* img  = (const float*)d_in[0];
    const float* kern = (const float*)d_in[1];
    const float* offh = (const float*)d_in[2];
    const float* offv = (const float*)d_in[3];
    const float* ou   = (const float*)d_in[4];
    float* out = (float*)d_out;

    dim3 block(256);
    dim3 grid(B * HO);   // 2048 blocks: 16x16-output tiles, XCD-swizzled by batch
    hipLaunchKernelGGL(ds_lds, grid, block, 0, stream,
                       img, kern, offh, offv, ou, out);
}